// Round 3
// baseline (725.140 us; speedup 1.0000x reference)
//
#include <hip/hip_runtime.h>
#include <math.h>

// Differentiable A* forward (training mode), N=4096, Tmax=1024.
// R15 = R9 verbatim + speculative next-row prefetch (zero semantic risk).
// Post-mortems R13 (+197 cy/step) and R14 (+92 cy/step): anything ADDED to
// the always-executed backedge (unconditional child blocks, ballot counter
// feeding the loop condition) costs real time. The only lever left is
// REMOVING latency from the loop-carried chain using work placed in existing
// stall shadows.
// R15: the standing-frontier winner M_spec = wave_max(fmax(bmx,kx)) depends
// only on the step-top DS reads (ready ~150 cy) and fits entirely in the
// gather/fexp stall window where the wave idles -> free. The true next
// winner differs from decode(M_spec) only when a just-opened fresh child
// wins this very step (expected ~Sum 1/(t+1) ~ ln(Tmax) ~ 7-30 steps total:
// children's f drifts up by +0.5*E[w], so the standing frontier dominates).
// So: ind_pred = decode(M_spec); issue next step's CSR row load ~250 cy
// early; at next step top use prefetched regs on hit (uniform s_cmp) or
// reload on rare miss. `ind` still comes from the UNmodified R9 M1
// reduction -- the prediction only drives a prefetch, so state evolution
// is bit-identical by construction.
// Chain model: D = (500-D) + 310 -> ~405 vs 530 cy-equiv (-24%).
//  - bit-packed monotone keys: K = 0x3FF0...0 | (fe_bits<<12) | (4095-j);
//    positive-double ordering == u64 bit ordering -> argmax + exact global
//    first-index tiebreak in ONE f64 DPP wave-max; encode/decode = int ops.
//  - header-less CSR rows padded to CAP with col=r (inert at own expansion).
//  - incremental frontier: 64 block-max keys in LDS; per-step patch of the
//    expanded block (K_b) + fresh-child keys folded in registers.
//  - {g, par} packed float2; hist = per-lane closed bitmask registers;
//    backtrack with early-stop (walk cycles add no new marks).
// State-update chains bit-identical to R0 (absmax 0.0 across R1-R14).

#define NN    4096
#define TMAXI 1024
#define CAP   96     // entries/row, padded (deg ~ 41 +/- 6.4; 96 = +8.7 sigma)
#define STR9  96     // float2 stride/row = 768 B

__device__ __forceinline__ float fexp_of(float g, float h, float open) {
    // f = 0.5*g + 0.5*h ; f_exp = exp(-f/64) * open   (1/64 exact)
    float f = __fadd_rn(__fmul_rn(0.5f, g), __fmul_rn(0.5f, h));
    return __fmul_rn(expf(__fmul_rn(-f, 0.015625f)), open);
}

template <int CTRL, int RMASK>
__device__ __forceinline__ double dpp_mov_d(double x) {
    int lo = __double2loint(x), hi = __double2hiint(x);
    lo = __builtin_amdgcn_update_dpp(lo, lo, CTRL, RMASK, 0xf, false);
    hi = __builtin_amdgcn_update_dpp(hi, hi, CTRL, RMASK, 0xf, false);
    return __hiloint2double(hi, lo);
}

// 64-lane f64 max (operands in {0} U [1,2), no NaN); proven R3/R6/R9.
__device__ __forceinline__ double wave_max_f64(double x) {
    x = fmax(x, dpp_mov_d<0x111, 0xf>(x));   // row_shr:1
    x = fmax(x, dpp_mov_d<0x112, 0xf>(x));   // row_shr:2
    x = fmax(x, dpp_mov_d<0x114, 0xf>(x));   // row_shr:4
    x = fmax(x, dpp_mov_d<0x118, 0xf>(x));   // row_shr:8
    x = fmax(x, dpp_mov_d<0x142, 0xa>(x));   // bcast15
    x = fmax(x, dpp_mov_d<0x143, 0xc>(x));   // bcast31
    int lo = __builtin_amdgcn_readlane(__double2loint(x), 63);
    int hi = __builtin_amdgcn_readlane(__double2hiint(x), 63);
    return __hiloint2double(hi, lo);
}

// ---------------- preprocessing: wadj -> padded CSR (no header) -------------
__global__ __launch_bounds__(256)
void build_csr9(const float* __restrict__ wadj, float2* __restrict__ ent)
{
    __shared__ int lcnt;
    const int r = blockIdx.x;
    if (threadIdx.x == 0) lcnt = 0;
    __syncthreads();
    const float4* wrow = (const float4*)(wadj + (size_t)r * NN);
    for (int c = 0; c < NN / (256 * 4); ++c) {
        int t4 = c * 256 + threadIdx.x;
        float4 w4 = wrow[t4];
        float wv[4] = {w4.x, w4.y, w4.z, w4.w};
        #pragma unroll
        for (int k = 0; k < 4; ++k) {
            int col = t4 * 4 + k;
            float w = wv[k];
            if (col != r && w != 0.0f && !isinf(w)) {
                int p = atomicAdd(&lcnt, 1);
                if (p < CAP)
                    ent[(size_t)r * STR9 + p] =
                        make_float2(__int_as_float(col), w);
            }
        }
    }
    __syncthreads();
    // pad remaining slots with col = r (self; never fresh at expansion time)
    int base = min(lcnt, CAP);
    for (int p = base + (int)threadIdx.x; p < CAP; p += 256)
        ent[(size_t)r * STR9 + p] = make_float2(__int_as_float(r), 0.0f);
}

// ---------------- main search (1 block: wave0 search, wave1 L2 prefetch) ----
__global__ __launch_bounds__(128, 1)
void astar_fwd9(const int* __restrict__ start_p,
                const int* __restrict__ goal_p,
                const float* __restrict__ cost_maps,
                const float* __restrict__ wadj,
                const float2* __restrict__ ent,
                float* __restrict__ scratch,
                float* __restrict__ out)
{
    __shared__ __align__(16) unsigned long long ls_key[NN];  // 32 KB
    __shared__ __align__(16) float2 ls_gp[NN];               // 32 KB {g,par}
    __shared__ __align__(16) float ls_h[NN];                 // reused as pm
    __shared__ __align__(16) unsigned long long ls_bm[64];   // block max keys

    const int tid = threadIdx.x;

    if (tid >= 64) {
        // ---- prefetch wave: stream CSR into this XCD's L2, then exit ----
        const float4* p = (const float4*)ent;
        const int total = NN * (STR9 / 2);
        float acc = 0.0f;
        int l = tid - 64;
        #pragma unroll 4
        for (int i = l; i < total; i += 64) acc += p[i].x;
        scratch[l] = acc;                       // defeat DCE
        return;
    }

    const int lane  = tid;
    const int start = start_p[0];
    const int goal  = goal_p[0];

    // ---- init ----
    {
        const float4* c4 = (const float4*)cost_maps;
        const float4* w4 = (const float4*)(wadj + (size_t)start * NN);
        const float gf = (float)goal;
        for (int c = 0; c < NN / (64 * 4); ++c) {
            int j4 = c * 64 + lane;
            float4 hv4 = c4[j4];
            float4 gv4 = w4[j4];
            if (start >= j4 * 4 && start < j4 * 4 + 4)
                ((float*)&gv4)[start - j4 * 4] = 0.0f;   // diag zeroed
            ((float4*)ls_h)[j4] = hv4;
            float gv[4] = {gv4.x, gv4.y, gv4.z, gv4.w};
            #pragma unroll
            for (int k = 0; k < 4; ++k)
                ls_gp[j4 * 4 + k] = make_float2(gv[k], gf);
        }
        for (int c = 0; c < (int)(NN * sizeof(unsigned long long) /
                                  (64 * sizeof(float4))); ++c)
            ((float4*)ls_key)[c * 64 + lane] = make_float4(0.f, 0.f, 0.f, 0.f);
        ls_bm[lane] = 0ull;
        if (lane == 0) {
            float fe = fexp_of(0.0f, ls_h[start], 1.0f);  // g0[start]=0, open=1
            unsigned long long kb = 0x3FF0000000000000ull
                | ((unsigned long long)__float_as_uint(fe) << 12)
                | (unsigned)(4095 - start);
            ls_key[start] = kb;
            ls_bm[start >> 6] = kb;
        }
    }

    int ind = start;            // step 0 expands start (only open node)
    unsigned long long closedm = 0ull;
    int tf = 0;

    // ---- spec-prefetch state: prologue predicts start (always a hit) ----
    int ind_pred = start;
    float2 e0s, e1s = make_float2(0.0f, 0.0f);
    {
        const float2* prow = ent + (size_t)start * STR9;
        e0s = prow[lane];
        if (lane < 32) e1s = prow[64 + lane];
    }

    for (int t = 0; t < TMAXI; ++t) {
        const int b = ind >> 6;

        // ---- row regs: prefetched on hit (common), reload on rare miss ----
        float2 e0, e1;
        if (ind == ind_pred) {                   // wave-uniform s_cmp
            e0 = e0s;
            e1 = e1s;
        } else {
            const float2* row = ent + (size_t)ind * STR9;
            e0 = row[lane];
            e1 = make_float2(0.0f, 0.0f);
            if (lane < 32) e1 = row[64 + lane];
        }

        // ---- DS reads up front ----
        double bm_v = __longlong_as_double((long long)ls_bm[lane]);
        double kb_v = __longlong_as_double(
                          (long long)ls_key[(b << 6) + lane]);
        float  gind = ls_gp[ind].x;

        // ---- K_b: block-b max excluding ind ----
        double kx = kb_v;
        if (lane == (ind & 63)) kx = 0.0;
        if (kx <= 1.0) kx = 0.0;
        double K_b = wave_max_f64(kx);

        // ---- close ind (plain writes BEFORE child atomics; DS in-order) ----
        if (lane == 0) {
            ls_key[ind] = 0x3FF0000000000000ull;   // sentinel 1.0 (closed)
            ls_bm[b] = (unsigned long long)__double_as_longlong(K_b);
        }
        if (lane == b) closedm |= (1ull << (ind & 63));

        // ---- SPEC (in the gather/fexp stall shadow): standing-frontier
        //      winner -> issue next step's row load ~250 cy early. Drives
        //      ONLY a prefetch; `ind` still comes from the R9 M1 below. ----
        double bmx = (lane == b) ? 0.0 : bm_v;
        {
            double Ms = wave_max_f64(fmax(bmx, kx));
            int ip;
            if (Ms > 1.0) {
                unsigned long long mbs =
                    (unsigned long long)__double_as_longlong(Ms);
                ip = 4095 - (int)(mbs & 0xFFFu);
            } else {
                ip = 0;
            }
            ind_pred = __builtin_amdgcn_readfirstlane(ip);
            const float2* srow = ent + (size_t)ind_pred * STR9;
            e0s = srow[lane];
            if (lane < 32) e1s = srow[64 + lane];
        }

        const float indf = (float)ind;
        double nk0 = 0.0, nk1 = 0.0;

        // ---- open fresh neighbors (key==0): g=fl(gind+w), par=ind ----
        {
            int j = __float_as_int(e0.x);
            unsigned long long kj = ls_key[j];
            float hj = ls_h[j];
            if (kj == 0ull) {                  // untouched (pads: j==ind open/closed)
                float g2 = __fadd_rn(gind, e0.y);
                float fe = fexp_of(g2, hj, 1.0f);
                unsigned long long kb = 0x3FF0000000000000ull
                    | ((unsigned long long)__float_as_uint(fe) << 12)
                    | (unsigned)(4095 - j);
                ls_gp[j]  = make_float2(g2, indf);
                ls_key[j] = kb;
                atomicMax(&ls_bm[j >> 6], kb);
                nk0 = __longlong_as_double((long long)kb);
            }
        }
        if (lane < 32) {
            int j = __float_as_int(e1.x);
            unsigned long long kj = ls_key[j];
            float hj = ls_h[j];
            if (kj == 0ull) {
                float g2 = __fadd_rn(gind, e1.y);
                float fe = fexp_of(g2, hj, 1.0f);
                unsigned long long kb = 0x3FF0000000000000ull
                    | ((unsigned long long)__float_as_uint(fe) << 12)
                    | (unsigned)(4095 - j);
                ls_gp[j]  = make_float2(g2, indf);
                ls_key[j] = kb;
                atomicMax(&ls_bm[j >> 6], kb);
                nk1 = __longlong_as_double((long long)kb);
            }
        }

        tf = t;
        if (ind == goal) break;             // snm==1.0 >= 1e-8 always

        // ---- fused winner reduction over {bmx, kx, nk0, nk1} (R9 exact) ----
        double loc = fmax(fmax(bmx, kx), fmax(nk0, nk1));
        double M1 = wave_max_f64(loc);      // critical path
        int ind_next;
        if (M1 > 1.0) {
            unsigned long long mb = (unsigned long long)__double_as_longlong(M1);
            ind_next = 4095 - (int)(mb & 0xFFFu);
        } else {
            ind_next = 0;                   // no open nodes: argmax(0s) = 0
        }
        ind = __builtin_amdgcn_readfirstlane(ind_next);
    }

    // ---- outputs: hist from closed masks; path marks with early-stop ----
    ls_bm[lane] = closedm;                  // exchange masks via LDS
    for (int c = 0; c < NN / (64 * 4); ++c) // reuse ls_h as path-mark array
        ((float4*)ls_h)[c * 64 + lane] = make_float4(0.f, 0.f, 0.f, 0.f);
    if (lane == 0) {
        ls_h[goal] = 1.0f;
        int loc = (int)ls_gp[goal].y;
        for (int i = 0; i < tf; ++i) {
            if (ls_h[loc] != 0.0f) break;   // walk repeats: no new marks
            ls_h[loc] = 1.0f;
            loc = (int)ls_gp[loc].y;
        }
    }
    for (int c = 0; c < NN / (64 * 4); ++c) {
        int j4 = c * 64 + lane;
        unsigned long long m = ls_bm[j4 >> 4];
        unsigned int bits = (unsigned int)(m >> ((j4 & 15) * 4)) & 0xFu;
        float4 hist4;
        hist4.x = (bits & 1u) ? 1.0f : 0.0f;
        hist4.y = (bits & 2u) ? 1.0f : 0.0f;
        hist4.z = (bits & 4u) ? 1.0f : 0.0f;
        hist4.w = (bits & 8u) ? 1.0f : 0.0f;
        ((float4*)out)[j4]        = hist4;
        ((float4*)(out + NN))[j4] = ((const float4*)ls_h)[j4];
    }
}

// ---------------- R0 dense fallback (no workspace needed) -------------------
__device__ __forceinline__ float clip01(float x) {
    return fminf(fmaxf(x, 0.0f), 1.0f);
}

__global__ __launch_bounds__(1024, 1)
void astar_fwd(const int* __restrict__ start_p,
               const int* __restrict__ goal_p,
               const float* __restrict__ cost_maps,
               const float* __restrict__ adj,
               const float* __restrict__ wadj,
               float* __restrict__ out)
{
    __shared__ __align__(16) float ls_open[NN];
    __shared__ __align__(16) float ls_hist[NN];
    __shared__ __align__(16) float ls_g[NN];
    __shared__ __align__(16) float ls_par[NN];
    __shared__ __align__(16) float ls_fe[NN];
    __shared__ __align__(16) float ls_h[NN];
    __shared__ float red_v[16];
    __shared__ float red_s[16];
    __shared__ int   red_i[16];
    __shared__ float bc_snm, bc_gind;
    __shared__ int   bc_ind, ls_done, ls_tf;

    const int tid   = threadIdx.x;
    const int start = start_p[0];
    const int goal  = goal_p[0];

    for (int k = 0; k < 4; ++k) {
        int j = tid * 4 + k;
        float hv = cost_maps[j];
        float gv = wadj[(size_t)start * NN + j];
        if (j == start) gv = 0.0f;
        float ov = (j == start) ? 1.0f : 0.0f;
        ls_h[j] = hv; ls_g[j] = gv; ls_open[j] = ov;
        ls_hist[j] = 0.0f; ls_par[j] = (float)goal;
        ls_fe[j] = fexp_of(gv, hv, ov);
    }
    if (tid == 0) { ls_done = 0; ls_tf = 0; }
    __syncthreads();

    for (int t = 0; t < TMAXI; ++t) {
        float4 fe4 = *(const float4*)&ls_fe[tid * 4];
        float v0 = fe4.x, v1 = fe4.y, v2 = fe4.z, v3 = fe4.w;
        float sum = ((v0 + v1) + v2) + v3;
        float best = v0; int bi = tid * 4;
        if (v1 > best) { best = v1; bi = tid * 4 + 1; }
        if (v2 > best) { best = v2; bi = tid * 4 + 2; }
        if (v3 > best) { best = v3; bi = tid * 4 + 3; }
        #pragma unroll
        for (int off = 32; off > 0; off >>= 1) {
            float ov = __shfl_down(best, off);
            int   oi = __shfl_down(bi, off);
            float os = __shfl_down(sum, off);
            sum += os;
            if (ov > best || (ov == best && oi < bi)) { best = ov; bi = oi; }
        }
        if ((tid & 63) == 0) {
            int w = tid >> 6;
            red_v[w] = best; red_s[w] = sum; red_i[w] = bi;
        }
        __syncthreads();
        if (tid == 0) {
            float denom = red_s[0]; best = red_v[0]; bi = red_i[0];
            #pragma unroll
            for (int w = 1; w < 16; ++w) {
                denom += red_s[w];
                if (red_v[w] > best || (red_v[w] == best && red_i[w] < bi)) {
                    best = red_v[w]; bi = red_i[w];
                }
            }
            int ind = bi;
            float dg = (denom == 0.0f) ? 1.0f : denom;
            float y_ind = ls_fe[ind] / dg;
            float snm = __fadd_rn(__fsub_rn(1.0f, y_ind), y_ind);
            ls_open[ind] = clip01(__fsub_rn(ls_open[ind], snm));
            ls_hist[ind] = clip01(__fadd_rn(ls_hist[ind], snm));
            ls_fe[ind]   = fexp_of(ls_g[ind], ls_h[ind], ls_open[ind]);
            bc_ind = ind; bc_snm = snm; bc_gind = ls_g[ind];
            ls_tf = t;
            if (ind == goal && snm >= 1e-8f) ls_done = 1;
        }
        __syncthreads();
        {
            const int   ind  = bc_ind;
            const float snm  = bc_snm;
            const float gind = bc_gind;
            const float indf = (float)ind;
            float4 a4 = ((const float4*)(adj  + (size_t)ind * NN))[tid];
            float4 w4 = ((const float4*)(wadj + (size_t)ind * NN))[tid];
            float av[4] = {a4.x, a4.y, a4.z, a4.w};
            float wvv[4] = {w4.x, w4.y, w4.z, w4.w};
            #pragma unroll
            for (int k = 0; k < 4; ++k) {
                int j = tid * 4 + k;
                float a = av[k], w = wvv[k];
                if (j == ind) { a = 0.0f; w = 0.0f; }
                if (a != 0.0f) {
                    float o = ls_open[j], hi = ls_hist[j], gj = ls_g[j];
                    float one_o = __fsub_rn(1.0f, o);
                    float one_h = __fsub_rn(1.0f, hi);
                    float sm    = __fmul_rn(snm, a);
                    float neigh = __fmul_rn(__fmul_rn(sm, one_o), one_h);
                    float g2    = __fadd_rn(gind, w);
                    float cmp   = (gj > g2) ? 1.0f : 0.0f;
                    float s   = __fadd_rn(__fmul_rn(one_o, one_h),
                                          __fmul_rn(o, cmp));
                    float idx = __fmul_rn(s, neigh);
                    if (idx != 0.0f) {
                        float omi = __fsub_rn(1.0f, idx);
                        float gn = __fadd_rn(__fmul_rn(g2, idx),
                                             __fmul_rn(gj, omi));
                        float on = clip01(__fadd_rn(o, idx));
                        float pn = __fadd_rn(__fmul_rn(indf, idx),
                                             __fmul_rn(ls_par[j], omi));
                        ls_g[j] = gn; ls_open[j] = on; ls_par[j] = pn;
                        ls_fe[j] = fexp_of(gn, ls_h[j], on);
                    }
                }
            }
        }
        __syncthreads();
        if (ls_done) break;
    }

    for (int k = 0; k < 4; ++k) {
        int j = tid * 4 + k;
        out[j] = ls_hist[j];
        out[NN + j] = (j == goal) ? 1.0f : 0.0f;
    }
    __syncthreads();
    if (tid == 0) {
        int tfv = ls_tf;
        int loc = (int)ls_par[goal];
        for (int i = 0; i < tfv; ++i) {
            out[NN + loc] = 1.0f;
            loc = (int)ls_par[loc];
        }
    }
}

extern "C" void kernel_launch(void* const* d_in, const int* in_sizes, int n_in,
                              void* d_out, int out_size, void* d_ws, size_t ws_size,
                              hipStream_t stream)
{
    const int*   start_p = (const int*)d_in[0];
    const int*   goal_p  = (const int*)d_in[1];
    const float* cost    = (const float*)d_in[2];
    // d_in[3] = nodes (coords) — unused
    const float* adj     = (const float*)d_in[4];
    const float* wadj    = (const float*)d_in[5];
    float* out = (float*)d_out;

    const size_t csr_bytes = (size_t)NN * STR9 * sizeof(float2);  // 3.0 MB
    const size_t need = csr_bytes + 64 * sizeof(float);
    if (ws_size >= need) {
        float2* ent     = (float2*)d_ws;
        float*  scratch = (float*)((char*)d_ws + csr_bytes);
        build_csr9<<<dim3(NN), dim3(256), 0, stream>>>(wadj, ent);
        astar_fwd9<<<dim3(1), dim3(128), 0, stream>>>(start_p, goal_p, cost,
                                                      wadj, ent, scratch, out);
    } else {
        astar_fwd<<<dim3(1), dim3(1024), 0, stream>>>(start_p, goal_p, cost,
                                                      adj, wadj, out);
    }
}

// Round 4
// 568.904 us; speedup vs baseline: 1.2746x; 1.2746x over previous
//
#include <hip/hip_runtime.h>
#include <math.h>

// Differentiable A* forward (training mode), N=4096, Tmax=1024.
// R16 = R9 arithmetic, rescheduled under the PROGRAM-ORDER ISSUE MODEL.
// Post-mortems R13/R14/R15 established: single wave = in-order issue; every
// dependent VALU chain costs its full serial time regardless of "criticality";
// only memory latency can be hidden, and only behind LATER independent code.
// R9 step in issue order (~matches measured 1018 cy): kb stall 120 + kx 10 +
// K_b DPP chain 130 + close 20 + kj0 stall 120 + fexp 65 + kj1 stall 120
// (compiler can't hoist past group-0 aliasing stores) + fexp 50 + fold 15 +
// M1 chain 130 + decode 35 + loop 50.
// R16 changes (scheduling only, zero arithmetic change):
//  1. Hoist group-1 gathers next to group-0's (cols unique per row; pads
//     point at ind whose key is nonzero; group-0 stores never touch any j1)
//     -> two 120-cy gather stalls become one.
//  2. Merge K_b into the winner reduction as a second INTERLEAVED DPP chain
//     (wave_max2_f64). chainB = max(kx, fresh-children-in-block-b); written
//     to ls_bm[b] AFTER the child atomicMax ops -- final value identical to
//     R9's max(K_b_top, children-in-b) since plain write >= every atomic.
//     Removes a full ~130-cy serial chain.
//  3. Software-pipeline next step's row VMEM + {bm_v, kb_v, gind} DS reads
//     into the loop tail right after ind_next decode. No LDS write crosses
//     the old-top -> new-tail motion (next sentinel write comes after, as in
//     R9); LDS alias conservatism pins compiler order.
// State-update chains bit-identical to R0 (absmax 0.0 across R1-R15).
//  - bit-packed monotone keys: K = 0x3FF0...0 | (fe_bits<<12) | (4095-j);
//    positive-double ordering == u64 bit ordering -> argmax + exact global
//    first-index tiebreak in ONE f64 DPP wave-max; encode/decode = int ops.
//  - header-less CSR rows padded to CAP with col=r (inert at own expansion).
//  - incremental frontier: 64 block-max keys in LDS; per-step patch of the
//    expanded block + fresh-child keys folded in registers.
//  - {g, par} packed float2; hist = per-lane closed bitmask registers;
//    backtrack with early-stop (walk cycles add no new marks).

#define NN    4096
#define TMAXI 1024
#define CAP   96     // entries/row, padded (deg ~ 41 +/- 6.4; 96 = +8.7 sigma)
#define STR9  96     // float2 stride/row = 768 B

__device__ __forceinline__ float fexp_of(float g, float h, float open) {
    // f = 0.5*g + 0.5*h ; f_exp = exp(-f/64) * open   (1/64 exact)
    float f = __fadd_rn(__fmul_rn(0.5f, g), __fmul_rn(0.5f, h));
    return __fmul_rn(expf(__fmul_rn(-f, 0.015625f)), open);
}

template <int CTRL, int RMASK>
__device__ __forceinline__ double dpp_mov_d(double x) {
    int lo = __double2loint(x), hi = __double2hiint(x);
    lo = __builtin_amdgcn_update_dpp(lo, lo, CTRL, RMASK, 0xf, false);
    hi = __builtin_amdgcn_update_dpp(hi, hi, CTRL, RMASK, 0xf, false);
    return __hiloint2double(hi, lo);
}

// 64-lane f64 max (operands in {0} U [1,2), no NaN); proven R3/R6/R9.
__device__ __forceinline__ double wave_max_f64(double x) {
    x = fmax(x, dpp_mov_d<0x111, 0xf>(x));   // row_shr:1
    x = fmax(x, dpp_mov_d<0x112, 0xf>(x));   // row_shr:2
    x = fmax(x, dpp_mov_d<0x114, 0xf>(x));   // row_shr:4
    x = fmax(x, dpp_mov_d<0x118, 0xf>(x));   // row_shr:8
    x = fmax(x, dpp_mov_d<0x142, 0xa>(x));   // bcast15
    x = fmax(x, dpp_mov_d<0x143, 0xc>(x));   // bcast31
    int lo = __builtin_amdgcn_readlane(__double2loint(x), 63);
    int hi = __builtin_amdgcn_readlane(__double2hiint(x), 63);
    return __hiloint2double(hi, lo);
}

// Two interleaved 64-lane f64 maxes: independent chains alternate stages so
// the second chain's dependent latency hides under the first's. Same math
// per chain as wave_max_f64.
__device__ __forceinline__ void wave_max2_f64(double& a, double& b) {
    a = fmax(a, dpp_mov_d<0x111, 0xf>(a));
    b = fmax(b, dpp_mov_d<0x111, 0xf>(b));
    a = fmax(a, dpp_mov_d<0x112, 0xf>(a));
    b = fmax(b, dpp_mov_d<0x112, 0xf>(b));
    a = fmax(a, dpp_mov_d<0x114, 0xf>(a));
    b = fmax(b, dpp_mov_d<0x114, 0xf>(b));
    a = fmax(a, dpp_mov_d<0x118, 0xf>(a));
    b = fmax(b, dpp_mov_d<0x118, 0xf>(b));
    a = fmax(a, dpp_mov_d<0x142, 0xa>(a));
    b = fmax(b, dpp_mov_d<0x142, 0xa>(b));
    a = fmax(a, dpp_mov_d<0x143, 0xc>(a));
    b = fmax(b, dpp_mov_d<0x143, 0xc>(b));
    int alo = __builtin_amdgcn_readlane(__double2loint(a), 63);
    int ahi = __builtin_amdgcn_readlane(__double2hiint(a), 63);
    int blo = __builtin_amdgcn_readlane(__double2loint(b), 63);
    int bhi = __builtin_amdgcn_readlane(__double2hiint(b), 63);
    a = __hiloint2double(ahi, alo);
    b = __hiloint2double(bhi, blo);
}

// ---------------- preprocessing: wadj -> padded CSR (no header) -------------
__global__ __launch_bounds__(256)
void build_csr9(const float* __restrict__ wadj, float2* __restrict__ ent)
{
    __shared__ int lcnt;
    const int r = blockIdx.x;
    if (threadIdx.x == 0) lcnt = 0;
    __syncthreads();
    const float4* wrow = (const float4*)(wadj + (size_t)r * NN);
    for (int c = 0; c < NN / (256 * 4); ++c) {
        int t4 = c * 256 + threadIdx.x;
        float4 w4 = wrow[t4];
        float wv[4] = {w4.x, w4.y, w4.z, w4.w};
        #pragma unroll
        for (int k = 0; k < 4; ++k) {
            int col = t4 * 4 + k;
            float w = wv[k];
            if (col != r && w != 0.0f && !isinf(w)) {
                int p = atomicAdd(&lcnt, 1);
                if (p < CAP)
                    ent[(size_t)r * STR9 + p] =
                        make_float2(__int_as_float(col), w);
            }
        }
    }
    __syncthreads();
    // pad remaining slots with col = r (self; never fresh at expansion time)
    int base = min(lcnt, CAP);
    for (int p = base + (int)threadIdx.x; p < CAP; p += 256)
        ent[(size_t)r * STR9 + p] = make_float2(__int_as_float(r), 0.0f);
}

// ---------------- main search (1 block: wave0 search, wave1 L2 prefetch) ----
__global__ __launch_bounds__(128, 1)
void astar_fwd9(const int* __restrict__ start_p,
                const int* __restrict__ goal_p,
                const float* __restrict__ cost_maps,
                const float* __restrict__ wadj,
                const float2* __restrict__ ent,
                float* __restrict__ scratch,
                float* __restrict__ out)
{
    __shared__ __align__(16) unsigned long long ls_key[NN];  // 32 KB
    __shared__ __align__(16) float2 ls_gp[NN];               // 32 KB {g,par}
    __shared__ __align__(16) float ls_h[NN];                 // reused as pm
    __shared__ __align__(16) unsigned long long ls_bm[64];   // block max keys

    const int tid = threadIdx.x;

    if (tid >= 64) {
        // ---- prefetch wave: stream CSR into this XCD's L2, then exit ----
        const float4* p = (const float4*)ent;
        const int total = NN * (STR9 / 2);
        float acc = 0.0f;
        int l = tid - 64;
        #pragma unroll 4
        for (int i = l; i < total; i += 64) acc += p[i].x;
        scratch[l] = acc;                       // defeat DCE
        return;
    }

    const int lane  = tid;
    const int start = start_p[0];
    const int goal  = goal_p[0];

    // ---- init ----
    {
        const float4* c4 = (const float4*)cost_maps;
        const float4* w4 = (const float4*)(wadj + (size_t)start * NN);
        const float gf = (float)goal;
        for (int c = 0; c < NN / (64 * 4); ++c) {
            int j4 = c * 64 + lane;
            float4 hv4 = c4[j4];
            float4 gv4 = w4[j4];
            if (start >= j4 * 4 && start < j4 * 4 + 4)
                ((float*)&gv4)[start - j4 * 4] = 0.0f;   // diag zeroed
            ((float4*)ls_h)[j4] = hv4;
            float gv[4] = {gv4.x, gv4.y, gv4.z, gv4.w};
            #pragma unroll
            for (int k = 0; k < 4; ++k)
                ls_gp[j4 * 4 + k] = make_float2(gv[k], gf);
        }
        for (int c = 0; c < (int)(NN * sizeof(unsigned long long) /
                                  (64 * sizeof(float4))); ++c)
            ((float4*)ls_key)[c * 64 + lane] = make_float4(0.f, 0.f, 0.f, 0.f);
        ls_bm[lane] = 0ull;
        if (lane == 0) {
            float fe = fexp_of(0.0f, ls_h[start], 1.0f);  // g0[start]=0, open=1
            unsigned long long kb = 0x3FF0000000000000ull
                | ((unsigned long long)__float_as_uint(fe) << 12)
                | (unsigned)(4095 - start);
            ls_key[start] = kb;
            ls_bm[start >> 6] = kb;
        }
    }

    int ind = start;            // step 0 expands start (only open node)
    int b   = start >> 6;
    unsigned long long closedm = 0ull;
    int tf = 0;

    // ---- pipeline prologue: step-0 row VMEM + step-top DS reads ----
    float2 e0, e1;
    double bm_v, kb_v;
    float  gind;
    {
        const float2* row = ent + (size_t)start * STR9;
        e0 = row[lane];
        e1 = make_float2(0.0f, 0.0f);
        if (lane < 32) e1 = row[64 + lane];
        bm_v = __longlong_as_double((long long)ls_bm[lane]);
        kb_v = __longlong_as_double((long long)ls_key[(b << 6) + lane]);
        gind = ls_gp[ind].x;
    }

    for (int t = 0; t < TMAXI; ++t) {
        // ---- frontier candidates from pipelined reads ----
        double kx = kb_v;
        if (lane == (ind & 63)) kx = 0.0;
        if (kx <= 1.0) kx = 0.0;
        double bmx = (lane == b) ? 0.0 : bm_v;

        // ---- close ind (sentinel before any future block-b key read) ----
        if (lane == 0) ls_key[ind] = 0x3FF0000000000000ull;
        if (lane == b) closedm |= (1ull << (ind & 63));

        // ---- BOTH groups' gathers issued together (one latency window).
        //      Legal: cols unique per row; pads -> j==ind, key nonzero;
        //      group-0 stores below never touch any j1. ----
        const float indf = (float)ind;
        int j0 = __float_as_int(e0.x);
        int j1 = __float_as_int(e1.x);      // lanes>=32: e1.x==0.0 -> j1=0
        unsigned long long kj0 = ls_key[j0];
        unsigned long long kj1 = ls_key[j1];
        float hj0 = ls_h[j0];
        float hj1 = ls_h[j1];

        double nk0 = 0.0, nk1 = 0.0;

        // ---- open fresh neighbors (key==0): g=fl(gind+w), par=ind ----
        if (kj0 == 0ull) {                  // untouched (pads never fresh)
            float g2 = __fadd_rn(gind, e0.y);
            float fe = fexp_of(g2, hj0, 1.0f);
            unsigned long long kb = 0x3FF0000000000000ull
                | ((unsigned long long)__float_as_uint(fe) << 12)
                | (unsigned)(4095 - j0);
            ls_gp[j0]  = make_float2(g2, indf);
            ls_key[j0] = kb;
            atomicMax(&ls_bm[j0 >> 6], kb);
            nk0 = __longlong_as_double((long long)kb);
        }
        if (lane < 32 && kj1 == 0ull) {
            float g2 = __fadd_rn(gind, e1.y);
            float fe = fexp_of(g2, hj1, 1.0f);
            unsigned long long kb = 0x3FF0000000000000ull
                | ((unsigned long long)__float_as_uint(fe) << 12)
                | (unsigned)(4095 - j1);
            ls_gp[j1]  = make_float2(g2, indf);
            ls_key[j1] = kb;
            atomicMax(&ls_bm[j1 >> 6], kb);
            nk1 = __longlong_as_double((long long)kb);
        }

        tf = t;
        if (ind == goal) break;             // snm==1.0 >= 1e-8 always

        // ---- merged reduction: chainA = next winner (R9's M1 operands),
        //      chainB = repaired block-b max = max(kx, fresh children in b).
        //      Interleaved DPP chains; one latency window for both. ----
        double cA = fmax(fmax(bmx, kx), fmax(nk0, nk1));
        double cb0 = ((j0 >> 6) == b) ? nk0 : 0.0;   // nk==0 when not fresh
        double cb1 = ((j1 >> 6) == b) ? nk1 : 0.0;
        double cB = fmax(kx, fmax(cb0, cb1));
        wave_max2_f64(cA, cB);

        int ind_next;
        if (cA > 1.0) {
            unsigned long long mb = (unsigned long long)__double_as_longlong(cA);
            ind_next = 4095 - (int)(mb & 0xFFFu);
        } else {
            ind_next = 0;                   // no open nodes: argmax(0s) = 0
        }
        const int b_old = b;
        ind = __builtin_amdgcn_readfirstlane(ind_next);
        b   = ind >> 6;

        // ---- repair ls_bm[b_old] (plain write AFTER child atomics; value
        //      folds children-in-b so write >= every atomic -> final value
        //      identical to R9's). Must precede tail bm_v read (in-order). --
        if (lane == 0)
            ls_bm[b_old] = (unsigned long long)__double_as_longlong(cB);

        // ---- pipelined tail: issue next step's row VMEM + DS reads now so
        //      their latency overlaps decode/branch/top. No intervening LDS
        //      writes between here and old top-read position. ----
        const float2* row = ent + (size_t)ind * STR9;
        e0 = row[lane];
        e1 = make_float2(0.0f, 0.0f);
        if (lane < 32) e1 = row[64 + lane];
        bm_v = __longlong_as_double((long long)ls_bm[lane]);
        kb_v = __longlong_as_double((long long)ls_key[(b << 6) + lane]);
        gind = ls_gp[ind].x;
    }

    // ---- outputs: hist from closed masks; path marks with early-stop ----
    ls_bm[lane] = closedm;                  // exchange masks via LDS
    for (int c = 0; c < NN / (64 * 4); ++c) // reuse ls_h as path-mark array
        ((float4*)ls_h)[c * 64 + lane] = make_float4(0.f, 0.f, 0.f, 0.f);
    if (lane == 0) {
        ls_h[goal] = 1.0f;
        int loc = (int)ls_gp[goal].y;
        for (int i = 0; i < tf; ++i) {
            if (ls_h[loc] != 0.0f) break;   // walk repeats: no new marks
            ls_h[loc] = 1.0f;
            loc = (int)ls_gp[loc].y;
        }
    }
    for (int c = 0; c < NN / (64 * 4); ++c) {
        int j4 = c * 64 + lane;
        unsigned long long m = ls_bm[j4 >> 4];
        unsigned int bits = (unsigned int)(m >> ((j4 & 15) * 4)) & 0xFu;
        float4 hist4;
        hist4.x = (bits & 1u) ? 1.0f : 0.0f;
        hist4.y = (bits & 2u) ? 1.0f : 0.0f;
        hist4.z = (bits & 4u) ? 1.0f : 0.0f;
        hist4.w = (bits & 8u) ? 1.0f : 0.0f;
        ((float4*)out)[j4]        = hist4;
        ((float4*)(out + NN))[j4] = ((const float4*)ls_h)[j4];
    }
}

// ---------------- R0 dense fallback (no workspace needed) -------------------
__device__ __forceinline__ float clip01(float x) {
    return fminf(fmaxf(x, 0.0f), 1.0f);
}

__global__ __launch_bounds__(1024, 1)
void astar_fwd(const int* __restrict__ start_p,
               const int* __restrict__ goal_p,
               const float* __restrict__ cost_maps,
               const float* __restrict__ adj,
               const float* __restrict__ wadj,
               float* __restrict__ out)
{
    __shared__ __align__(16) float ls_open[NN];
    __shared__ __align__(16) float ls_hist[NN];
    __shared__ __align__(16) float ls_g[NN];
    __shared__ __align__(16) float ls_par[NN];
    __shared__ __align__(16) float ls_fe[NN];
    __shared__ __align__(16) float ls_h[NN];
    __shared__ float red_v[16];
    __shared__ float red_s[16];
    __shared__ int   red_i[16];
    __shared__ float bc_snm, bc_gind;
    __shared__ int   bc_ind, ls_done, ls_tf;

    const int tid   = threadIdx.x;
    const int start = start_p[0];
    const int goal  = goal_p[0];

    for (int k = 0; k < 4; ++k) {
        int j = tid * 4 + k;
        float hv = cost_maps[j];
        float gv = wadj[(size_t)start * NN + j];
        if (j == start) gv = 0.0f;
        float ov = (j == start) ? 1.0f : 0.0f;
        ls_h[j] = hv; ls_g[j] = gv; ls_open[j] = ov;
        ls_hist[j] = 0.0f; ls_par[j] = (float)goal;
        ls_fe[j] = fexp_of(gv, hv, ov);
    }
    if (tid == 0) { ls_done = 0; ls_tf = 0; }
    __syncthreads();

    for (int t = 0; t < TMAXI; ++t) {
        float4 fe4 = *(const float4*)&ls_fe[tid * 4];
        float v0 = fe4.x, v1 = fe4.y, v2 = fe4.z, v3 = fe4.w;
        float sum = ((v0 + v1) + v2) + v3;
        float best = v0; int bi = tid * 4;
        if (v1 > best) { best = v1; bi = tid * 4 + 1; }
        if (v2 > best) { best = v2; bi = tid * 4 + 2; }
        if (v3 > best) { best = v3; bi = tid * 4 + 3; }
        #pragma unroll
        for (int off = 32; off > 0; off >>= 1) {
            float ov = __shfl_down(best, off);
            int   oi = __shfl_down(bi, off);
            float os = __shfl_down(sum, off);
            sum += os;
            if (ov > best || (ov == best && oi < bi)) { best = ov; bi = oi; }
        }
        if ((tid & 63) == 0) {
            int w = tid >> 6;
            red_v[w] = best; red_s[w] = sum; red_i[w] = bi;
        }
        __syncthreads();
        if (tid == 0) {
            float denom = red_s[0]; best = red_v[0]; bi = red_i[0];
            #pragma unroll
            for (int w = 1; w < 16; ++w) {
                denom += red_s[w];
                if (red_v[w] > best || (red_v[w] == best && red_i[w] < bi)) {
                    best = red_v[w]; bi = red_i[w];
                }
            }
            int ind = bi;
            float dg = (denom == 0.0f) ? 1.0f : denom;
            float y_ind = ls_fe[ind] / dg;
            float snm = __fadd_rn(__fsub_rn(1.0f, y_ind), y_ind);
            ls_open[ind] = clip01(__fsub_rn(ls_open[ind], snm));
            ls_hist[ind] = clip01(__fadd_rn(ls_hist[ind], snm));
            ls_fe[ind]   = fexp_of(ls_g[ind], ls_h[ind], ls_open[ind]);
            bc_ind = ind; bc_snm = snm; bc_gind = ls_g[ind];
            ls_tf = t;
            if (ind == goal && snm >= 1e-8f) ls_done = 1;
        }
        __syncthreads();
        {
            const int   ind  = bc_ind;
            const float snm  = bc_snm;
            const float gind = bc_gind;
            const float indf = (float)ind;
            float4 a4 = ((const float4*)(adj  + (size_t)ind * NN))[tid];
            float4 w4 = ((const float4*)(wadj + (size_t)ind * NN))[tid];
            float av[4] = {a4.x, a4.y, a4.z, a4.w};
            float wvv[4] = {w4.x, w4.y, w4.z, w4.w};
            #pragma unroll
            for (int k = 0; k < 4; ++k) {
                int j = tid * 4 + k;
                float a = av[k], w = wvv[k];
                if (j == ind) { a = 0.0f; w = 0.0f; }
                if (a != 0.0f) {
                    float o = ls_open[j], hi = ls_hist[j], gj = ls_g[j];
                    float one_o = __fsub_rn(1.0f, o);
                    float one_h = __fsub_rn(1.0f, hi);
                    float sm    = __fmul_rn(snm, a);
                    float neigh = __fmul_rn(__fmul_rn(sm, one_o), one_h);
                    float g2    = __fadd_rn(gind, w);
                    float cmp   = (gj > g2) ? 1.0f : 0.0f;
                    float s   = __fadd_rn(__fmul_rn(one_o, one_h),
                                          __fmul_rn(o, cmp));
                    float idx = __fmul_rn(s, neigh);
                    if (idx != 0.0f) {
                        float omi = __fsub_rn(1.0f, idx);
                        float gn = __fadd_rn(__fmul_rn(g2, idx),
                                             __fmul_rn(gj, omi));
                        float on = clip01(__fadd_rn(o, idx));
                        float pn = __fadd_rn(__fmul_rn(indf, idx),
                                             __fmul_rn(ls_par[j], omi));
                        ls_g[j] = gn; ls_open[j] = on; ls_par[j] = pn;
                        ls_fe[j] = fexp_of(gn, ls_h[j], on);
                    }
                }
            }
        }
        __syncthreads();
        if (ls_done) break;
    }

    for (int k = 0; k < 4; ++k) {
        int j = tid * 4 + k;
        out[j] = ls_hist[j];
        out[NN + j] = (j == goal) ? 1.0f : 0.0f;
    }
    __syncthreads();
    if (tid == 0) {
        int tfv = ls_tf;
        int loc = (int)ls_par[goal];
        for (int i = 0; i < tfv; ++i) {
            out[NN + loc] = 1.0f;
            loc = (int)ls_par[loc];
        }
    }
}

extern "C" void kernel_launch(void* const* d_in, const int* in_sizes, int n_in,
                              void* d_out, int out_size, void* d_ws, size_t ws_size,
                              hipStream_t stream)
{
    const int*   start_p = (const int*)d_in[0];
    const int*   goal_p  = (const int*)d_in[1];
    const float* cost    = (const float*)d_in[2];
    // d_in[3] = nodes (coords) — unused
    const float* adj     = (const float*)d_in[4];
    const float* wadj    = (const float*)d_in[5];
    float* out = (float*)d_out;

    const size_t csr_bytes = (size_t)NN * STR9 * sizeof(float2);  // 3.0 MB
    const size_t need = csr_bytes + 64 * sizeof(float);
    if (ws_size >= need) {
        float2* ent     = (float2*)d_ws;
        float*  scratch = (float*)((char*)d_ws + csr_bytes);
        build_csr9<<<dim3(NN), dim3(256), 0, stream>>>(wadj, ent);
        astar_fwd9<<<dim3(1), dim3(128), 0, stream>>>(start_p, goal_p, cost,
                                                      wadj, ent, scratch, out);
    } else {
        astar_fwd<<<dim3(1), dim3(1024), 0, stream>>>(start_p, goal_p, cost,
                                                      adj, wadj, out);
    }
}

// Round 5
// 564.372 us; speedup vs baseline: 1.2849x; 1.0080x over previous
//
#include <hip/hip_runtime.h>
#include <math.h>

// Differentiable A* forward (training mode), N=4096, Tmax=1024.
// R17 = R9 search wave VERBATIM + 7-wave fast L2 prefetch (block 128->512).
// Post-mortem chain R13-R16: all VALU/DS rescheduling of the step is neutral
// or negative; R16 (gather hoist + merged DPP chains + pipelined tail) moved
// 1018 -> 1036 cy/step. The ~400 cy/step unexplained by the issue-order model
// (~625 cy) is row-VMEM latency class: the single prefetch wave (4 KB in
// flight, ~11 GB/s) needs ~275 us to stream the 3 MB CSR -- still running
// for 2/3 of the search -- so ~half the (random-index) row loads pay L3/HBM
// latency (~600-900 cy) instead of L2 (~220). Counter evidence: FETCH_SIZE
// 1561 KB ~ half the CSR fetched from beyond L2 (build_csr9's dirty lines
// are scattered over all 8 non-coherent XCD L2s). Model closes:
// 625 + 0.5*(~800-220) ~ 1015 ~ measured 1018.
// R17: waves 1-7 stream the CSR interleaved (stride 448 lanes, unroll 8,
// ~56 KB in flight) -> warm in ~20-30 us, then exit. Search wave untouched.
//  - bit-packed monotone keys: K = 0x3FF0...0 | (fe_bits<<12) | (4095-j);
//    positive-double ordering == u64 bit ordering -> argmax + exact global
//    first-index tiebreak in ONE f64 DPP wave-max; encode/decode = int ops.
//  - header-less CSR rows padded to CAP with col=r (inert at own expansion).
//  - incremental frontier: 64 block-max keys in LDS; per-step patch of the
//    expanded block (K_b) + fresh-child keys folded in registers.
//  - {g, par} packed float2; hist = per-lane closed bitmask registers;
//    backtrack with early-stop (walk cycles add no new marks).
// State-update chains bit-identical to R0 (absmax 0.0 across R1-R16).

#define NN    4096
#define TMAXI 1024
#define CAP   96     // entries/row, padded (deg ~ 41 +/- 6.4; 96 = +8.7 sigma)
#define STR9  96     // float2 stride/row = 768 B

__device__ __forceinline__ float fexp_of(float g, float h, float open) {
    // f = 0.5*g + 0.5*h ; f_exp = exp(-f/64) * open   (1/64 exact)
    float f = __fadd_rn(__fmul_rn(0.5f, g), __fmul_rn(0.5f, h));
    return __fmul_rn(expf(__fmul_rn(-f, 0.015625f)), open);
}

template <int CTRL, int RMASK>
__device__ __forceinline__ double dpp_mov_d(double x) {
    int lo = __double2loint(x), hi = __double2hiint(x);
    lo = __builtin_amdgcn_update_dpp(lo, lo, CTRL, RMASK, 0xf, false);
    hi = __builtin_amdgcn_update_dpp(hi, hi, CTRL, RMASK, 0xf, false);
    return __hiloint2double(hi, lo);
}

// 64-lane f64 max (operands in {0} U [1,2), no NaN); proven R3/R6/R9.
__device__ __forceinline__ double wave_max_f64(double x) {
    x = fmax(x, dpp_mov_d<0x111, 0xf>(x));   // row_shr:1
    x = fmax(x, dpp_mov_d<0x112, 0xf>(x));   // row_shr:2
    x = fmax(x, dpp_mov_d<0x114, 0xf>(x));   // row_shr:4
    x = fmax(x, dpp_mov_d<0x118, 0xf>(x));   // row_shr:8
    x = fmax(x, dpp_mov_d<0x142, 0xa>(x));   // bcast15
    x = fmax(x, dpp_mov_d<0x143, 0xc>(x));   // bcast31
    int lo = __builtin_amdgcn_readlane(__double2loint(x), 63);
    int hi = __builtin_amdgcn_readlane(__double2hiint(x), 63);
    return __hiloint2double(hi, lo);
}

// ---------------- preprocessing: wadj -> padded CSR (no header) -------------
__global__ __launch_bounds__(256)
void build_csr9(const float* __restrict__ wadj, float2* __restrict__ ent)
{
    __shared__ int lcnt;
    const int r = blockIdx.x;
    if (threadIdx.x == 0) lcnt = 0;
    __syncthreads();
    const float4* wrow = (const float4*)(wadj + (size_t)r * NN);
    for (int c = 0; c < NN / (256 * 4); ++c) {
        int t4 = c * 256 + threadIdx.x;
        float4 w4 = wrow[t4];
        float wv[4] = {w4.x, w4.y, w4.z, w4.w};
        #pragma unroll
        for (int k = 0; k < 4; ++k) {
            int col = t4 * 4 + k;
            float w = wv[k];
            if (col != r && w != 0.0f && !isinf(w)) {
                int p = atomicAdd(&lcnt, 1);
                if (p < CAP)
                    ent[(size_t)r * STR9 + p] =
                        make_float2(__int_as_float(col), w);
            }
        }
    }
    __syncthreads();
    // pad remaining slots with col = r (self; never fresh at expansion time)
    int base = min(lcnt, CAP);
    for (int p = base + (int)threadIdx.x; p < CAP; p += 256)
        ent[(size_t)r * STR9 + p] = make_float2(__int_as_float(r), 0.0f);
}

// ------------- main search (1 block: wave0 search, waves 1-7 prefetch) ------
__global__ __launch_bounds__(512, 1)
void astar_fwd9(const int* __restrict__ start_p,
                const int* __restrict__ goal_p,
                const float* __restrict__ cost_maps,
                const float* __restrict__ wadj,
                const float2* __restrict__ ent,
                float* __restrict__ scratch,
                float* __restrict__ out)
{
    __shared__ __align__(16) unsigned long long ls_key[NN];  // 32 KB
    __shared__ __align__(16) float2 ls_gp[NN];               // 32 KB {g,par}
    __shared__ __align__(16) float ls_h[NN];                 // reused as pm
    __shared__ __align__(16) unsigned long long ls_bm[64];   // block max keys

    const int tid = threadIdx.x;

    if (tid >= 64) {
        // ---- 7 prefetch waves: stream CSR into this XCD's L2 FAST, exit.
        //      448 lanes x unroll 8 ~ 56 KB in flight -> ~20-30 us for 3 MB
        //      (vs ~275 us for R9's single wave = the measured bottleneck). --
        const float4* p = (const float4*)ent;
        const int total = NN * (STR9 / 2);
        float acc = 0.0f;
        int l = tid - 64;                       // 0..447
        #pragma unroll 8
        for (int i = l; i < total; i += 448) acc += p[i].x;
        scratch[l & 63] = acc;                  // defeat DCE (races benign)
        return;
    }

    const int lane  = tid;
    const int start = start_p[0];
    const int goal  = goal_p[0];

    // ---- init ----
    {
        const float4* c4 = (const float4*)cost_maps;
        const float4* w4 = (const float4*)(wadj + (size_t)start * NN);
        const float gf = (float)goal;
        for (int c = 0; c < NN / (64 * 4); ++c) {
            int j4 = c * 64 + lane;
            float4 hv4 = c4[j4];
            float4 gv4 = w4[j4];
            if (start >= j4 * 4 && start < j4 * 4 + 4)
                ((float*)&gv4)[start - j4 * 4] = 0.0f;   // diag zeroed
            ((float4*)ls_h)[j4] = hv4;
            float gv[4] = {gv4.x, gv4.y, gv4.z, gv4.w};
            #pragma unroll
            for (int k = 0; k < 4; ++k)
                ls_gp[j4 * 4 + k] = make_float2(gv[k], gf);
        }
        for (int c = 0; c < (int)(NN * sizeof(unsigned long long) /
                                  (64 * sizeof(float4))); ++c)
            ((float4*)ls_key)[c * 64 + lane] = make_float4(0.f, 0.f, 0.f, 0.f);
        ls_bm[lane] = 0ull;
        if (lane == 0) {
            float fe = fexp_of(0.0f, ls_h[start], 1.0f);  // g0[start]=0, open=1
            unsigned long long kb = 0x3FF0000000000000ull
                | ((unsigned long long)__float_as_uint(fe) << 12)
                | (unsigned)(4095 - start);
            ls_key[start] = kb;
            ls_bm[start >> 6] = kb;
        }
    }

    int ind = start;            // step 0 expands start (only open node)
    unsigned long long closedm = 0ull;
    int tf = 0;

    for (int t = 0; t < TMAXI; ++t) {
        const int b = ind >> 6;

        // ---- issue all latency ops up front (row VMEM + three DS reads) ----
        const float2* row = ent + (size_t)ind * STR9;
        float2 e0 = row[lane];
        float2 e1 = make_float2(0.0f, 0.0f);
        if (lane < 32) e1 = row[64 + lane];
        double bm_v = __longlong_as_double((long long)ls_bm[lane]);
        double kb_v = __longlong_as_double(
                          (long long)ls_key[(b << 6) + lane]);
        float  gind = ls_gp[ind].x;

        // ---- K_b: block-b max excluding ind (overlaps row VMEM) ----
        double kx = kb_v;
        if (lane == (ind & 63)) kx = 0.0;
        if (kx <= 1.0) kx = 0.0;
        double K_b = wave_max_f64(kx);

        // ---- close ind (plain writes BEFORE child atomics; DS in-order) ----
        if (lane == 0) {
            ls_key[ind] = 0x3FF0000000000000ull;   // sentinel 1.0 (closed)
            ls_bm[b] = (unsigned long long)__double_as_longlong(K_b);
        }
        if (lane == b) closedm |= (1ull << (ind & 63));

        const float indf = (float)ind;
        double nk0 = 0.0, nk1 = 0.0;

        // ---- open fresh neighbors (key==0): g=fl(gind+w), par=ind ----
        {
            int j = __float_as_int(e0.x);
            unsigned long long kj = ls_key[j];
            float hj = ls_h[j];
            if (kj == 0ull) {                  // untouched (pads: j==ind open/closed)
                float g2 = __fadd_rn(gind, e0.y);
                float fe = fexp_of(g2, hj, 1.0f);
                unsigned long long kb = 0x3FF0000000000000ull
                    | ((unsigned long long)__float_as_uint(fe) << 12)
                    | (unsigned)(4095 - j);
                ls_gp[j]  = make_float2(g2, indf);
                ls_key[j] = kb;
                atomicMax(&ls_bm[j >> 6], kb);
                nk0 = __longlong_as_double((long long)kb);
            }
        }
        if (lane < 32) {
            int j = __float_as_int(e1.x);
            unsigned long long kj = ls_key[j];
            float hj = ls_h[j];
            if (kj == 0ull) {
                float g2 = __fadd_rn(gind, e1.y);
                float fe = fexp_of(g2, hj, 1.0f);
                unsigned long long kb = 0x3FF0000000000000ull
                    | ((unsigned long long)__float_as_uint(fe) << 12)
                    | (unsigned)(4095 - j);
                ls_gp[j]  = make_float2(g2, indf);
                ls_key[j] = kb;
                atomicMax(&ls_bm[j >> 6], kb);
                nk1 = __longlong_as_double((long long)kb);
            }
        }

        tf = t;
        if (ind == goal) break;             // snm==1.0 >= 1e-8 always

        // ---- fused winner reduction over {bmx, kx, nk0, nk1} ----
        double bmx = (lane == b) ? 0.0 : bm_v;
        double loc = fmax(fmax(bmx, kx), fmax(nk0, nk1));
        double M1 = wave_max_f64(loc);      // critical path
        int ind_next;
        if (M1 > 1.0) {
            unsigned long long mb = (unsigned long long)__double_as_longlong(M1);
            ind_next = 4095 - (int)(mb & 0xFFFu);
        } else {
            ind_next = 0;                   // no open nodes: argmax(0s) = 0
        }
        ind = __builtin_amdgcn_readfirstlane(ind_next);
    }

    // ---- outputs: hist from closed masks; path marks with early-stop ----
    ls_bm[lane] = closedm;                  // exchange masks via LDS
    for (int c = 0; c < NN / (64 * 4); ++c) // reuse ls_h as path-mark array
        ((float4*)ls_h)[c * 64 + lane] = make_float4(0.f, 0.f, 0.f, 0.f);
    if (lane == 0) {
        ls_h[goal] = 1.0f;
        int loc = (int)ls_gp[goal].y;
        for (int i = 0; i < tf; ++i) {
            if (ls_h[loc] != 0.0f) break;   // walk repeats: no new marks
            ls_h[loc] = 1.0f;
            loc = (int)ls_gp[loc].y;
        }
    }
    for (int c = 0; c < NN / (64 * 4); ++c) {
        int j4 = c * 64 + lane;
        unsigned long long m = ls_bm[j4 >> 4];
        unsigned int bits = (unsigned int)(m >> ((j4 & 15) * 4)) & 0xFu;
        float4 hist4;
        hist4.x = (bits & 1u) ? 1.0f : 0.0f;
        hist4.y = (bits & 2u) ? 1.0f : 0.0f;
        hist4.z = (bits & 4u) ? 1.0f : 0.0f;
        hist4.w = (bits & 8u) ? 1.0f : 0.0f;
        ((float4*)out)[j4]        = hist4;
        ((float4*)(out + NN))[j4] = ((const float4*)ls_h)[j4];
    }
}

// ---------------- R0 dense fallback (no workspace needed) -------------------
__device__ __forceinline__ float clip01(float x) {
    return fminf(fmaxf(x, 0.0f), 1.0f);
}

__global__ __launch_bounds__(1024, 1)
void astar_fwd(const int* __restrict__ start_p,
               const int* __restrict__ goal_p,
               const float* __restrict__ cost_maps,
               const float* __restrict__ adj,
               const float* __restrict__ wadj,
               float* __restrict__ out)
{
    __shared__ __align__(16) float ls_open[NN];
    __shared__ __align__(16) float ls_hist[NN];
    __shared__ __align__(16) float ls_g[NN];
    __shared__ __align__(16) float ls_par[NN];
    __shared__ __align__(16) float ls_fe[NN];
    __shared__ __align__(16) float ls_h[NN];
    __shared__ float red_v[16];
    __shared__ float red_s[16];
    __shared__ int   red_i[16];
    __shared__ float bc_snm, bc_gind;
    __shared__ int   bc_ind, ls_done, ls_tf;

    const int tid   = threadIdx.x;
    const int start = start_p[0];
    const int goal  = goal_p[0];

    for (int k = 0; k < 4; ++k) {
        int j = tid * 4 + k;
        float hv = cost_maps[j];
        float gv = wadj[(size_t)start * NN + j];
        if (j == start) gv = 0.0f;
        float ov = (j == start) ? 1.0f : 0.0f;
        ls_h[j] = hv; ls_g[j] = gv; ls_open[j] = ov;
        ls_hist[j] = 0.0f; ls_par[j] = (float)goal;
        ls_fe[j] = fexp_of(gv, hv, ov);
    }
    if (tid == 0) { ls_done = 0; ls_tf = 0; }
    __syncthreads();

    for (int t = 0; t < TMAXI; ++t) {
        float4 fe4 = *(const float4*)&ls_fe[tid * 4];
        float v0 = fe4.x, v1 = fe4.y, v2 = fe4.z, v3 = fe4.w;
        float sum = ((v0 + v1) + v2) + v3;
        float best = v0; int bi = tid * 4;
        if (v1 > best) { best = v1; bi = tid * 4 + 1; }
        if (v2 > best) { best = v2; bi = tid * 4 + 2; }
        if (v3 > best) { best = v3; bi = tid * 4 + 3; }
        #pragma unroll
        for (int off = 32; off > 0; off >>= 1) {
            float ov = __shfl_down(best, off);
            int   oi = __shfl_down(bi, off);
            float os = __shfl_down(sum, off);
            sum += os;
            if (ov > best || (ov == best && oi < bi)) { best = ov; bi = oi; }
        }
        if ((tid & 63) == 0) {
            int w = tid >> 6;
            red_v[w] = best; red_s[w] = sum; red_i[w] = bi;
        }
        __syncthreads();
        if (tid == 0) {
            float denom = red_s[0]; best = red_v[0]; bi = red_i[0];
            #pragma unroll
            for (int w = 1; w < 16; ++w) {
                denom += red_s[w];
                if (red_v[w] > best || (red_v[w] == best && red_i[w] < bi)) {
                    best = red_v[w]; bi = red_i[w];
                }
            }
            int ind = bi;
            float dg = (denom == 0.0f) ? 1.0f : denom;
            float y_ind = ls_fe[ind] / dg;
            float snm = __fadd_rn(__fsub_rn(1.0f, y_ind), y_ind);
            ls_open[ind] = clip01(__fsub_rn(ls_open[ind], snm));
            ls_hist[ind] = clip01(__fadd_rn(ls_hist[ind], snm));
            ls_fe[ind]   = fexp_of(ls_g[ind], ls_h[ind], ls_open[ind]);
            bc_ind = ind; bc_snm = snm; bc_gind = ls_g[ind];
            ls_tf = t;
            if (ind == goal && snm >= 1e-8f) ls_done = 1;
        }
        __syncthreads();
        {
            const int   ind  = bc_ind;
            const float snm  = bc_snm;
            const float gind = bc_gind;
            const float indf = (float)ind;
            float4 a4 = ((const float4*)(adj  + (size_t)ind * NN))[tid];
            float4 w4 = ((const float4*)(wadj + (size_t)ind * NN))[tid];
            float av[4] = {a4.x, a4.y, a4.z, a4.w};
            float wvv[4] = {w4.x, w4.y, w4.z, w4.w};
            #pragma unroll
            for (int k = 0; k < 4; ++k) {
                int j = tid * 4 + k;
                float a = av[k], w = wvv[k];
                if (j == ind) { a = 0.0f; w = 0.0f; }
                if (a != 0.0f) {
                    float o = ls_open[j], hi = ls_hist[j], gj = ls_g[j];
                    float one_o = __fsub_rn(1.0f, o);
                    float one_h = __fsub_rn(1.0f, hi);
                    float sm    = __fmul_rn(snm, a);
                    float neigh = __fmul_rn(__fmul_rn(sm, one_o), one_h);
                    float g2    = __fadd_rn(gind, w);
                    float cmp   = (gj > g2) ? 1.0f : 0.0f;
                    float s   = __fadd_rn(__fmul_rn(one_o, one_h),
                                          __fmul_rn(o, cmp));
                    float idx = __fmul_rn(s, neigh);
                    if (idx != 0.0f) {
                        float omi = __fsub_rn(1.0f, idx);
                        float gn = __fadd_rn(__fmul_rn(g2, idx),
                                             __fmul_rn(gj, omi));
                        float on = clip01(__fadd_rn(o, idx));
                        float pn = __fadd_rn(__fmul_rn(indf, idx),
                                             __fmul_rn(ls_par[j], omi));
                        ls_g[j] = gn; ls_open[j] = on; ls_par[j] = pn;
                        ls_fe[j] = fexp_of(gn, ls_h[j], on);
                    }
                }
            }
        }
        __syncthreads();
        if (ls_done) break;
    }

    for (int k = 0; k < 4; ++k) {
        int j = tid * 4 + k;
        out[j] = ls_hist[j];
        out[NN + j] = (j == goal) ? 1.0f : 0.0f;
    }
    __syncthreads();
    if (tid == 0) {
        int tfv = ls_tf;
        int loc = (int)ls_par[goal];
        for (int i = 0; i < tfv; ++i) {
            out[NN + loc] = 1.0f;
            loc = (int)ls_par[loc];
        }
    }
}

extern "C" void kernel_launch(void* const* d_in, const int* in_sizes, int n_in,
                              void* d_out, int out_size, void* d_ws, size_t ws_size,
                              hipStream_t stream)
{
    const int*   start_p = (const int*)d_in[0];
    const int*   goal_p  = (const int*)d_in[1];
    const float* cost    = (const float*)d_in[2];
    // d_in[3] = nodes (coords) — unused
    const float* adj     = (const float*)d_in[4];
    const float* wadj    = (const float*)d_in[5];
    float* out = (float*)d_out;

    const size_t csr_bytes = (size_t)NN * STR9 * sizeof(float2);  // 3.0 MB
    const size_t need = csr_bytes + 64 * sizeof(float);
    if (ws_size >= need) {
        float2* ent     = (float2*)d_ws;
        float*  scratch = (float*)((char*)d_ws + csr_bytes);
        build_csr9<<<dim3(NN), dim3(256), 0, stream>>>(wadj, ent);
        astar_fwd9<<<dim3(1), dim3(512), 0, stream>>>(start_p, goal_p, cost,
                                                      wadj, ent, scratch, out);
    } else {
        astar_fwd<<<dim3(1), dim3(1024), 0, stream>>>(start_p, goal_p, cost,
                                                      adj, wadj, out);
    }
}

// Round 6
// 559.445 us; speedup vs baseline: 1.2962x; 1.0088x over previous
//
#include <hip/hip_runtime.h>
#include <math.h>

// Differentiable A* forward (training mode), N=4096, Tmax=1024.
// R18 = final revert to R9/R12 exactly (proven best: ~434 us search /
// ~557 us total). Session evidence that this is the floor:
//   R13 de-serialized child gathers        -> +197 cy/step (execz predication
//       is load-bearing; unconditional blocks pay full issue cost)
//   R14 exact no-fresh endgame switch      -> +92 cy/step (backedge ballot->
//       SALU->branch chain costs more than the endgame saves)
//   R15 speculative next-row prefetch      -> +39% (a second DPP chain is
//       NOT free "in the stall shadow": single wave = in-order issue)
//   R16 gather hoist + merged K_b/M1 DPP chains + pipelined tail -> +2%
//       (the step time is INVARIANT under full rescheduling)
//   R17 7-wave fast L2 warm-up             -> +-0% (FETCH_SIZE unchanged;
//       rows already L2-warm from cross-dispatch retention)
// Conclusion: the loop-carried chain {ind -> row VMEM -> freshness gather ->
// fexp -> fused DPP wave-max -> decode -> ind} is the floor at ~1018 cy/step
// equivalent; every component has been intervened on directly with neutral
// or negative result. Counters at floor: VALUBusy 0.04%, HBM 0.05%,
// MfmaUtil 0, one wave resident. No harness-accessible lever remains
// (clock state not controllable; ablation probes would break absmax==0).
// Kernel structure (unchanged from R9):
//  - bit-packed monotone keys: K = 0x3FF0...0 | (fe_bits<<12) | (4095-j);
//    positive-double ordering == u64 bit ordering -> argmax + exact global
//    first-index tiebreak in ONE f64 DPP wave-max; encode/decode = int ops.
//  - header-less CSR rows padded to CAP with col=r (inert: r is open/closed,
//    never fresh, at its own expansion).
//  - incremental frontier: 64 block-max keys in LDS; per-step patch of the
//    expanded block (K_b) + fresh-child keys folded in registers.
//  - {g, par} packed float2; hist = per-lane closed bitmask registers;
//    backtrack with early-stop (walk cycles add no new marks).
// State-update chains bit-identical to R0 (absmax 0.0 across R1-R17):
// g=fl(gind+w), fe = exp(fl(-fl(0.5g+0.5h)*2^-6)) chain, par=ind exact,
// snm==1.0 proven exact (Sterbenz + rounding argument, R3).

#define NN    4096
#define TMAXI 1024
#define CAP   96     // entries/row, padded (deg ~ 41 +/- 6.4; 96 = +8.7 sigma)
#define STR9  96     // float2 stride/row = 768 B

__device__ __forceinline__ float fexp_of(float g, float h, float open) {
    // f = 0.5*g + 0.5*h ; f_exp = exp(-f/64) * open   (1/64 exact)
    float f = __fadd_rn(__fmul_rn(0.5f, g), __fmul_rn(0.5f, h));
    return __fmul_rn(expf(__fmul_rn(-f, 0.015625f)), open);
}

template <int CTRL, int RMASK>
__device__ __forceinline__ double dpp_mov_d(double x) {
    int lo = __double2loint(x), hi = __double2hiint(x);
    lo = __builtin_amdgcn_update_dpp(lo, lo, CTRL, RMASK, 0xf, false);
    hi = __builtin_amdgcn_update_dpp(hi, hi, CTRL, RMASK, 0xf, false);
    return __hiloint2double(hi, lo);
}

// 64-lane f64 max (operands in {0} U [1,2), no NaN); proven R3/R6/R9.
__device__ __forceinline__ double wave_max_f64(double x) {
    x = fmax(x, dpp_mov_d<0x111, 0xf>(x));   // row_shr:1
    x = fmax(x, dpp_mov_d<0x112, 0xf>(x));   // row_shr:2
    x = fmax(x, dpp_mov_d<0x114, 0xf>(x));   // row_shr:4
    x = fmax(x, dpp_mov_d<0x118, 0xf>(x));   // row_shr:8
    x = fmax(x, dpp_mov_d<0x142, 0xa>(x));   // bcast15
    x = fmax(x, dpp_mov_d<0x143, 0xc>(x));   // bcast31
    int lo = __builtin_amdgcn_readlane(__double2loint(x), 63);
    int hi = __builtin_amdgcn_readlane(__double2hiint(x), 63);
    return __hiloint2double(hi, lo);
}

// ---------------- preprocessing: wadj -> padded CSR (no header) -------------
__global__ __launch_bounds__(256)
void build_csr9(const float* __restrict__ wadj, float2* __restrict__ ent)
{
    __shared__ int lcnt;
    const int r = blockIdx.x;
    if (threadIdx.x == 0) lcnt = 0;
    __syncthreads();
    const float4* wrow = (const float4*)(wadj + (size_t)r * NN);
    for (int c = 0; c < NN / (256 * 4); ++c) {
        int t4 = c * 256 + threadIdx.x;
        float4 w4 = wrow[t4];
        float wv[4] = {w4.x, w4.y, w4.z, w4.w};
        #pragma unroll
        for (int k = 0; k < 4; ++k) {
            int col = t4 * 4 + k;
            float w = wv[k];
            if (col != r && w != 0.0f && !isinf(w)) {
                int p = atomicAdd(&lcnt, 1);
                if (p < CAP)
                    ent[(size_t)r * STR9 + p] =
                        make_float2(__int_as_float(col), w);
            }
        }
    }
    __syncthreads();
    // pad remaining slots with col = r (self; never fresh at expansion time)
    int base = min(lcnt, CAP);
    for (int p = base + (int)threadIdx.x; p < CAP; p += 256)
        ent[(size_t)r * STR9 + p] = make_float2(__int_as_float(r), 0.0f);
}

// ---------------- main search (1 block: wave0 search, wave1 L2 prefetch) ----
__global__ __launch_bounds__(128, 1)
void astar_fwd9(const int* __restrict__ start_p,
                const int* __restrict__ goal_p,
                const float* __restrict__ cost_maps,
                const float* __restrict__ wadj,
                const float2* __restrict__ ent,
                float* __restrict__ scratch,
                float* __restrict__ out)
{
    __shared__ __align__(16) unsigned long long ls_key[NN];  // 32 KB
    __shared__ __align__(16) float2 ls_gp[NN];               // 32 KB {g,par}
    __shared__ __align__(16) float ls_h[NN];                 // reused as pm
    __shared__ __align__(16) unsigned long long ls_bm[64];   // block max keys

    const int tid = threadIdx.x;

    if (tid >= 64) {
        // ---- prefetch wave: stream CSR into this XCD's L2, then exit ----
        const float4* p = (const float4*)ent;
        const int total = NN * (STR9 / 2);
        float acc = 0.0f;
        int l = tid - 64;
        #pragma unroll 4
        for (int i = l; i < total; i += 64) acc += p[i].x;
        scratch[l] = acc;                       // defeat DCE
        return;
    }

    const int lane  = tid;
    const int start = start_p[0];
    const int goal  = goal_p[0];

    // ---- init ----
    {
        const float4* c4 = (const float4*)cost_maps;
        const float4* w4 = (const float4*)(wadj + (size_t)start * NN);
        const float gf = (float)goal;
        for (int c = 0; c < NN / (64 * 4); ++c) {
            int j4 = c * 64 + lane;
            float4 hv4 = c4[j4];
            float4 gv4 = w4[j4];
            if (start >= j4 * 4 && start < j4 * 4 + 4)
                ((float*)&gv4)[start - j4 * 4] = 0.0f;   // diag zeroed
            ((float4*)ls_h)[j4] = hv4;
            float gv[4] = {gv4.x, gv4.y, gv4.z, gv4.w};
            #pragma unroll
            for (int k = 0; k < 4; ++k)
                ls_gp[j4 * 4 + k] = make_float2(gv[k], gf);
        }
        for (int c = 0; c < (int)(NN * sizeof(unsigned long long) /
                                  (64 * sizeof(float4))); ++c)
            ((float4*)ls_key)[c * 64 + lane] = make_float4(0.f, 0.f, 0.f, 0.f);
        ls_bm[lane] = 0ull;
        if (lane == 0) {
            float fe = fexp_of(0.0f, ls_h[start], 1.0f);  // g0[start]=0, open=1
            unsigned long long kb = 0x3FF0000000000000ull
                | ((unsigned long long)__float_as_uint(fe) << 12)
                | (unsigned)(4095 - start);
            ls_key[start] = kb;
            ls_bm[start >> 6] = kb;
        }
    }

    int ind = start;            // step 0 expands start (only open node)
    unsigned long long closedm = 0ull;
    int tf = 0;

    for (int t = 0; t < TMAXI; ++t) {
        const int b = ind >> 6;

        // ---- issue all latency ops up front (row VMEM + three DS reads) ----
        const float2* row = ent + (size_t)ind * STR9;
        float2 e0 = row[lane];
        float2 e1 = make_float2(0.0f, 0.0f);
        if (lane < 32) e1 = row[64 + lane];
        double bm_v = __longlong_as_double((long long)ls_bm[lane]);
        double kb_v = __longlong_as_double(
                          (long long)ls_key[(b << 6) + lane]);
        float  gind = ls_gp[ind].x;

        // ---- K_b: block-b max excluding ind (overlaps row VMEM) ----
        double kx = kb_v;
        if (lane == (ind & 63)) kx = 0.0;
        if (kx <= 1.0) kx = 0.0;
        double K_b = wave_max_f64(kx);

        // ---- close ind (plain writes BEFORE child atomics; DS in-order) ----
        if (lane == 0) {
            ls_key[ind] = 0x3FF0000000000000ull;   // sentinel 1.0 (closed)
            ls_bm[b] = (unsigned long long)__double_as_longlong(K_b);
        }
        if (lane == b) closedm |= (1ull << (ind & 63));

        const float indf = (float)ind;
        double nk0 = 0.0, nk1 = 0.0;

        // ---- open fresh neighbors (key==0): g=fl(gind+w), par=ind ----
        {
            int j = __float_as_int(e0.x);
            unsigned long long kj = ls_key[j];
            float hj = ls_h[j];
            if (kj == 0ull) {                  // untouched (pads: j==ind open/closed)
                float g2 = __fadd_rn(gind, e0.y);
                float fe = fexp_of(g2, hj, 1.0f);
                unsigned long long kb = 0x3FF0000000000000ull
                    | ((unsigned long long)__float_as_uint(fe) << 12)
                    | (unsigned)(4095 - j);
                ls_gp[j]  = make_float2(g2, indf);
                ls_key[j] = kb;
                atomicMax(&ls_bm[j >> 6], kb);
                nk0 = __longlong_as_double((long long)kb);
            }
        }
        if (lane < 32) {
            int j = __float_as_int(e1.x);
            unsigned long long kj = ls_key[j];
            float hj = ls_h[j];
            if (kj == 0ull) {
                float g2 = __fadd_rn(gind, e1.y);
                float fe = fexp_of(g2, hj, 1.0f);
                unsigned long long kb = 0x3FF0000000000000ull
                    | ((unsigned long long)__float_as_uint(fe) << 12)
                    | (unsigned)(4095 - j);
                ls_gp[j]  = make_float2(g2, indf);
                ls_key[j] = kb;
                atomicMax(&ls_bm[j >> 6], kb);
                nk1 = __longlong_as_double((long long)kb);
            }
        }

        tf = t;
        if (ind == goal) break;             // snm==1.0 >= 1e-8 always

        // ---- fused winner reduction over {bmx, kx, nk0, nk1} ----
        double bmx = (lane == b) ? 0.0 : bm_v;
        double loc = fmax(fmax(bmx, kx), fmax(nk0, nk1));
        double M1 = wave_max_f64(loc);      // critical path
        int ind_next;
        if (M1 > 1.0) {
            unsigned long long mb = (unsigned long long)__double_as_longlong(M1);
            ind_next = 4095 - (int)(mb & 0xFFFu);
        } else {
            ind_next = 0;                   // no open nodes: argmax(0s) = 0
        }
        ind = __builtin_amdgcn_readfirstlane(ind_next);
    }

    // ---- outputs: hist from closed masks; path marks with early-stop ----
    ls_bm[lane] = closedm;                  // exchange masks via LDS
    for (int c = 0; c < NN / (64 * 4); ++c) // reuse ls_h as path-mark array
        ((float4*)ls_h)[c * 64 + lane] = make_float4(0.f, 0.f, 0.f, 0.f);
    if (lane == 0) {
        ls_h[goal] = 1.0f;
        int loc = (int)ls_gp[goal].y;
        for (int i = 0; i < tf; ++i) {
            if (ls_h[loc] != 0.0f) break;   // walk repeats: no new marks
            ls_h[loc] = 1.0f;
            loc = (int)ls_gp[loc].y;
        }
    }
    for (int c = 0; c < NN / (64 * 4); ++c) {
        int j4 = c * 64 + lane;
        unsigned long long m = ls_bm[j4 >> 4];
        unsigned int bits = (unsigned int)(m >> ((j4 & 15) * 4)) & 0xFu;
        float4 hist4;
        hist4.x = (bits & 1u) ? 1.0f : 0.0f;
        hist4.y = (bits & 2u) ? 1.0f : 0.0f;
        hist4.z = (bits & 4u) ? 1.0f : 0.0f;
        hist4.w = (bits & 8u) ? 1.0f : 0.0f;
        ((float4*)out)[j4]        = hist4;
        ((float4*)(out + NN))[j4] = ((const float4*)ls_h)[j4];
    }
}

// ---------------- R0 dense fallback (no workspace needed) -------------------
__device__ __forceinline__ float clip01(float x) {
    return fminf(fmaxf(x, 0.0f), 1.0f);
}

__global__ __launch_bounds__(1024, 1)
void astar_fwd(const int* __restrict__ start_p,
               const int* __restrict__ goal_p,
               const float* __restrict__ cost_maps,
               const float* __restrict__ adj,
               const float* __restrict__ wadj,
               float* __restrict__ out)
{
    __shared__ __align__(16) float ls_open[NN];
    __shared__ __align__(16) float ls_hist[NN];
    __shared__ __align__(16) float ls_g[NN];
    __shared__ __align__(16) float ls_par[NN];
    __shared__ __align__(16) float ls_fe[NN];
    __shared__ __align__(16) float ls_h[NN];
    __shared__ float red_v[16];
    __shared__ float red_s[16];
    __shared__ int   red_i[16];
    __shared__ float bc_snm, bc_gind;
    __shared__ int   bc_ind, ls_done, ls_tf;

    const int tid   = threadIdx.x;
    const int start = start_p[0];
    const int goal  = goal_p[0];

    for (int k = 0; k < 4; ++k) {
        int j = tid * 4 + k;
        float hv = cost_maps[j];
        float gv = wadj[(size_t)start * NN + j];
        if (j == start) gv = 0.0f;
        float ov = (j == start) ? 1.0f : 0.0f;
        ls_h[j] = hv; ls_g[j] = gv; ls_open[j] = ov;
        ls_hist[j] = 0.0f; ls_par[j] = (float)goal;
        ls_fe[j] = fexp_of(gv, hv, ov);
    }
    if (tid == 0) { ls_done = 0; ls_tf = 0; }
    __syncthreads();

    for (int t = 0; t < TMAXI; ++t) {
        float4 fe4 = *(const float4*)&ls_fe[tid * 4];
        float v0 = fe4.x, v1 = fe4.y, v2 = fe4.z, v3 = fe4.w;
        float sum = ((v0 + v1) + v2) + v3;
        float best = v0; int bi = tid * 4;
        if (v1 > best) { best = v1; bi = tid * 4 + 1; }
        if (v2 > best) { best = v2; bi = tid * 4 + 2; }
        if (v3 > best) { best = v3; bi = tid * 4 + 3; }
        #pragma unroll
        for (int off = 32; off > 0; off >>= 1) {
            float ov = __shfl_down(best, off);
            int   oi = __shfl_down(bi, off);
            float os = __shfl_down(sum, off);
            sum += os;
            if (ov > best || (ov == best && oi < bi)) { best = ov; bi = oi; }
        }
        if ((tid & 63) == 0) {
            int w = tid >> 6;
            red_v[w] = best; red_s[w] = sum; red_i[w] = bi;
        }
        __syncthreads();
        if (tid == 0) {
            float denom = red_s[0]; best = red_v[0]; bi = red_i[0];
            #pragma unroll
            for (int w = 1; w < 16; ++w) {
                denom += red_s[w];
                if (red_v[w] > best || (red_v[w] == best && red_i[w] < bi)) {
                    best = red_v[w]; bi = red_i[w];
                }
            }
            int ind = bi;
            float dg = (denom == 0.0f) ? 1.0f : denom;
            float y_ind = ls_fe[ind] / dg;
            float snm = __fadd_rn(__fsub_rn(1.0f, y_ind), y_ind);
            ls_open[ind] = clip01(__fsub_rn(ls_open[ind], snm));
            ls_hist[ind] = clip01(__fadd_rn(ls_hist[ind], snm));
            ls_fe[ind]   = fexp_of(ls_g[ind], ls_h[ind], ls_open[ind]);
            bc_ind = ind; bc_snm = snm; bc_gind = ls_g[ind];
            ls_tf = t;
            if (ind == goal && snm >= 1e-8f) ls_done = 1;
        }
        __syncthreads();
        {
            const int   ind  = bc_ind;
            const float snm  = bc_snm;
            const float gind = bc_gind;
            const float indf = (float)ind;
            float4 a4 = ((const float4*)(adj  + (size_t)ind * NN))[tid];
            float4 w4 = ((const float4*)(wadj + (size_t)ind * NN))[tid];
            float av[4] = {a4.x, a4.y, a4.z, a4.w};
            float wvv[4] = {w4.x, w4.y, w4.z, w4.w};
            #pragma unroll
            for (int k = 0; k < 4; ++k) {
                int j = tid * 4 + k;
                float a = av[k], w = wvv[k];
                if (j == ind) { a = 0.0f; w = 0.0f; }
                if (a != 0.0f) {
                    float o = ls_open[j], hi = ls_hist[j], gj = ls_g[j];
                    float one_o = __fsub_rn(1.0f, o);
                    float one_h = __fsub_rn(1.0f, hi);
                    float sm    = __fmul_rn(snm, a);
                    float neigh = __fmul_rn(__fmul_rn(sm, one_o), one_h);
                    float g2    = __fadd_rn(gind, w);
                    float cmp   = (gj > g2) ? 1.0f : 0.0f;
                    float s   = __fadd_rn(__fmul_rn(one_o, one_h),
                                          __fmul_rn(o, cmp));
                    float idx = __fmul_rn(s, neigh);
                    if (idx != 0.0f) {
                        float omi = __fsub_rn(1.0f, idx);
                        float gn = __fadd_rn(__fmul_rn(g2, idx),
                                             __fmul_rn(gj, omi));
                        float on = clip01(__fadd_rn(o, idx));
                        float pn = __fadd_rn(__fmul_rn(indf, idx),
                                             __fmul_rn(ls_par[j], omi));
                        ls_g[j] = gn; ls_open[j] = on; ls_par[j] = pn;
                        ls_fe[j] = fexp_of(gn, ls_h[j], on);
                    }
                }
            }
        }
        __syncthreads();
        if (ls_done) break;
    }

    for (int k = 0; k < 4; ++k) {
        int j = tid * 4 + k;
        out[j] = ls_hist[j];
        out[NN + j] = (j == goal) ? 1.0f : 0.0f;
    }
    __syncthreads();
    if (tid == 0) {
        int tfv = ls_tf;
        int loc = (int)ls_par[goal];
        for (int i = 0; i < tfv; ++i) {
            out[NN + loc] = 1.0f;
            loc = (int)ls_par[loc];
        }
    }
}

extern "C" void kernel_launch(void* const* d_in, const int* in_sizes, int n_in,
                              void* d_out, int out_size, void* d_ws, size_t ws_size,
                              hipStream_t stream)
{
    const int*   start_p = (const int*)d_in[0];
    const int*   goal_p  = (const int*)d_in[1];
    const float* cost    = (const float*)d_in[2];
    // d_in[3] = nodes (coords) — unused
    const float* adj     = (const float*)d_in[4];
    const float* wadj    = (const float*)d_in[5];
    float* out = (float*)d_out;

    const size_t csr_bytes = (size_t)NN * STR9 * sizeof(float2);  // 3.0 MB
    const size_t need = csr_bytes + 64 * sizeof(float);
    if (ws_size >= need) {
        float2* ent     = (float2*)d_ws;
        float*  scratch = (float*)((char*)d_ws + csr_bytes);
        build_csr9<<<dim3(NN), dim3(256), 0, stream>>>(wadj, ent);
        astar_fwd9<<<dim3(1), dim3(128), 0, stream>>>(start_p, goal_p, cost,
                                                      wadj, ent, scratch, out);
    } else {
        astar_fwd<<<dim3(1), dim3(1024), 0, stream>>>(start_p, goal_p, cost,
                                                      adj, wadj, out);
    }
}